// Round 19
// baseline (607.568 us; speedup 1.0000x reference)
//
#include <hip/hip_runtime.h>
#include <hip/hip_bf16.h>

typedef __hip_bfloat16 bf16;

#define NT 50000
#define NP 50000
#define NE 200000
#define HH 8
#define DD 32
#define CC 256   // H*D
#define NBLK 196 // ceil(NT/256)

typedef short s8v __attribute__((ext_vector_type(8)));   // 8 bf16 (4 VGPRs)
typedef float f4v __attribute__((ext_vector_type(4)));   // 4 f32 acc

__device__ __forceinline__ float bu2f(unsigned short u) {
  return __uint_as_float(((unsigned)u) << 16);
}
__device__ __forceinline__ unsigned short f2bu(float x) {
  bf16 b = __float2bfloat16(x);
  return *(unsigned short*)&b;
}

__device__ __forceinline__ void gload_lds16(const void* g, void* l) {
  __builtin_amdgcn_global_load_lds(
      (const __attribute__((address_space(1))) void*)g,
      (__attribute__((address_space(3))) void*)l, 16, 0, 0);
}

// -------- input convert (both node matrices in one dispatch) --------
__global__ __launch_bounds__(256) void cvt2_f2b(
    const float* __restrict__ a, const float* __restrict__ b,
    bf16* __restrict__ oa, bf16* __restrict__ ob, int n) {
  int i = blockIdx.x * 256 + threadIdx.x;
  if (i >= n) return;
  if (blockIdx.y == 0) oa[i] = __float2bfloat16(a[i]);
  else                 ob[i] = __float2bfloat16(b[i]);
}

// -------- weight prep --------
// W1cat[l] (1024 x K) rows: [Ws rel0 | Wd rel0 | Wd rel1 | Ws rel2]
// W2cat[l] ( 512 x K) rows: [Ws rel1 | Wd rel2]
struct WtArgs {
  const float* Ws[3]; const float* Wd[3];
  bf16* W1[3]; bf16* W2[3];
};
__global__ __launch_bounds__(256) void wt_cvt_all(WtArgs a) {
  int l = blockIdx.z, y = blockIdx.y;
  int K = (l == 0) ? 128 : 256;
  int idx = blockIdx.x * 256 + threadIdx.x;
  if (idx >= 256 * K) return;
  int n = idx / K, k = idx - n * K;
  const float* W; bf16* D; int dn;
  if (y == 0)      { W = a.Ws[l];                       D = a.W1[l]; dn = n; }
  else if (y == 1) { W = a.Wd[l];                       D = a.W1[l]; dn = n + 256; }
  else if (y == 2) { W = a.Wd[l] + (size_t)1 * K * 256; D = a.W1[l]; dn = n + 512; }
  else if (y == 3) { W = a.Ws[l] + (size_t)2 * K * 256; D = a.W1[l]; dn = n + 768; }
  else if (y == 4) { W = a.Ws[l] + (size_t)1 * K * 256; D = a.W2[l]; dn = n; }
  else             { W = a.Wd[l] + (size_t)2 * K * 256; D = a.W2[l]; dn = n + 256; }
  D[(size_t)dn * K + k] = __float2bfloat16(W[(size_t)k * 256 + n]);
}

struct BiArgs {
  const float* bs[3]; const float* bd[3];
  float* b1; float* b2;  // b1: 3*1024, b2: 3*512
};
__global__ __launch_bounds__(256) void bias_cat(BiArgs a) {
  int l = blockIdx.y, y = blockIdx.x;
  int n = threadIdx.x;
  float v;
  if (y == 0)      v = a.bs[l][n];
  else if (y == 1) v = a.bd[l][n];
  else if (y == 2) v = a.bd[l][256 + n];
  else if (y == 3) v = a.bs[l][512 + n];
  else if (y == 4) v = a.bs[l][256 + n];
  else             v = a.bd[l][512 + n];
  if (y < 4) a.b1[l * 1024 + y * 256 + n] = v;
  else       a.b2[l * 512 + (y - 4) * 256 + n] = v;
}

__global__ __launch_bounds__(256) void zero_i(int* __restrict__ p, int n) {
  int i = blockIdx.x * 256 + threadIdx.x;
  if (i < n) p[i] = 0;
}

// -------- CSR build (batched over 3 relations via blockIdx.y) --------
__global__ __launch_bounds__(256) void hist3(
    const int* __restrict__ d0, const int* __restrict__ d1,
    const int* __restrict__ d2, int* __restrict__ deg) {
  int r = blockIdx.y;
  int e = blockIdx.x * 256 + threadIdx.x;
  if (e >= NE) return;
  const int* d = (r == 0) ? d0 : (r == 1) ? d1 : d2;
  atomicAdd(&deg[r * NT + d[e]], 1);
}

__global__ __launch_bounds__(256) void scan_s1(const int* __restrict__ deg,
                                               int* __restrict__ bsum) {
  __shared__ int buf[256];
  int r = blockIdx.y, b = blockIdx.x, t = threadIdx.x;
  int idx = b * 256 + t;
  buf[t] = (idx < NT) ? deg[r * NT + idx] : 0;
  __syncthreads();
  for (int s = 128; s > 0; s >>= 1) {
    if (t < s) buf[t] += buf[t + s];
    __syncthreads();
  }
  if (t == 0) bsum[r * NBLK + b] = buf[0];
}

__global__ __launch_bounds__(256) void scan_s2(
    const int* __restrict__ bsum, int* __restrict__ boff,
    int* __restrict__ offs) {
  __shared__ int buf[256];
  int t = threadIdx.x;
  for (int r = 0; r < 3; r++) {
    int v = (t < NBLK) ? bsum[r * NBLK + t] : 0;
    buf[t] = v;
    __syncthreads();
    for (int s = 1; s < 256; s <<= 1) {
      int u = (t >= s) ? buf[t - s] : 0;
      __syncthreads();
      buf[t] += u;
      __syncthreads();
    }
    if (t < NBLK) boff[r * NBLK + t] = buf[t] - v;
    if (t == 255) offs[(size_t)r * (NT + 1) + NT] = buf[255];
    __syncthreads();
  }
}

__global__ __launch_bounds__(256) void scan_s3(
    const int* __restrict__ deg, const int* __restrict__ boff,
    int* __restrict__ offs, int* __restrict__ cursor) {
  __shared__ int buf[256];
  int r = blockIdx.y, b = blockIdx.x, t = threadIdx.x;
  int idx = b * 256 + t;
  int v = (idx < NT) ? deg[r * NT + idx] : 0;
  buf[t] = v;
  __syncthreads();
  for (int s = 1; s < 256; s <<= 1) {
    int u = (t >= s) ? buf[t - s] : 0;
    __syncthreads();
    buf[t] += u;
    __syncthreads();
  }
  int o = boff[r * NBLK + b] + buf[t] - v;
  if (idx < NT) {
    offs[(size_t)r * (NT + 1) + idx] = o;
    cursor[r * NT + idx] = o;
  }
}

__global__ __launch_bounds__(256) void fill3(
    const int* __restrict__ d0, const int* __restrict__ d1,
    const int* __restrict__ d2, const int* __restrict__ s0,
    const int* __restrict__ s1, const int* __restrict__ s2,
    int* __restrict__ cursor, int* __restrict__ csrc) {
  int r = blockIdx.y;
  int e = blockIdx.x * 256 + threadIdx.x;
  if (e >= NE) return;
  const int* d = (r == 0) ? d0 : (r == 1) ? d1 : d2;
  const int* s = (r == 0) ? s0 : (r == 1) ? s1 : s2;
  int p = atomicAdd(&cursor[r * NT + d[e]], 1);
  csrc[(size_t)r * NE + p] = s[e];
}

// -------- 256x256 MFMA GEMM: A via LDS dbuf, B direct-to-register --------
// B panel is L2-resident (<=512KB); fragments loaded straight from global,
// double-buffered across the barrier so the barrier's vmcnt(0) drain hides
// their latency. Only A (the 25.6MB HBM read) is staged through LDS ->
// per-iteration drained staging bytes halve vs staging both.
__global__ __launch_bounds__(512, 2) void gemm256(
    const bf16* __restrict__ A1, const bf16* __restrict__ B1t,
    const float* __restrict__ bias1, bf16* __restrict__ C1,
    const bf16* __restrict__ A2, const bf16* __restrict__ B2t,
    const float* __restrict__ bias2, bf16* __restrict__ C2,
    int M, int K, int q8, int r8) {
  __shared__ short LDS[32768];  // A dbuf: 2 x 8192 shorts (32KB); epilogue overlays 64KB
  int bid = blockIdx.x;
  int xcd = bid & 7, pos = bid >> 3;
  int wg = (xcd < r8 ? xcd * (q8 + 1) : r8 * (q8 + 1) + (xcd - r8) * q8) + pos;
  int bm = wg / 6, bn = wg - bm * 6;

  const bf16* A; const bf16* Bt; const float* bias; bf16* Cout; int Ncols, col0;
  if (bn < 4) { A = A1; Bt = B1t + (size_t)bn * 256 * K; bias = bias1; Cout = C1; Ncols = 1024; col0 = bn * 256; }
  else { A = A2; Bt = B2t + (size_t)(bn - 4) * 256 * K; bias = bias2; Cout = C2; Ncols = 512; col0 = (bn - 4) * 256; }

  int t = threadIdx.x;
  int lane = t & 63;
  int wid = t >> 6;
  int wm = wid >> 2, wn = wid & 3;   // 2 x 4 wave grid
  int row0 = bm * 256;
  int wbase = t & ~63;

  f4v acc[4][8] = {};   // [i: N-frag][j: M-frag]

  const bf16* Abase = A + (size_t)row0 * K;

  auto stageA = [&](int buf, int kt) {
    int kofs = kt * 32;
    #pragma unroll
    for (int j = 0; j < 2; j++) {
      int s = j * 512 + t;
      int row = s >> 2, ch2 = s & 3;
      int sch = ch2 ^ ((row >> 1) & 3);
      gload_lds16(Abase + (size_t)row * K + kofs + sch * 8,
                  &LDS[buf * 8192 + (j * 512 + wbase) * 8]);
    }
  };

  int ch = lane >> 4;
  int rr = lane & 15;
  // lane's B fragment base: row = wn*64 + i*16 + rr, k-chunk ch
  const bf16* Bfrag = Bt + (size_t)(wn * 64 + rr) * K + ch * 8;

  int nk = K / 32;   // 4 or 8
  s8v af[4], afn[4];
  stageA(0, 0);
  #pragma unroll
  for (int i = 0; i < 4; i++)
    af[i] = *(const s8v*)(Bfrag + (size_t)i * 16 * K);
  __syncthreads();   // drains A stage + B loads

  int cur = 0;
  for (int kt = 0; kt < nk; kt++) {
    if (kt + 1 < nk) {
      stageA(cur ^ 1, kt + 1);
      #pragma unroll
      for (int i = 0; i < 4; i++)
        afn[i] = *(const s8v*)(Bfrag + (size_t)i * 16 * K + (kt + 1) * 32);
    }
    s8v bfv[8];
    #pragma unroll
    for (int j = 0; j < 8; j++) {
      int row = wm * 128 + j * 16 + rr;
      bfv[j] = *(const s8v*)&LDS[cur * 8192 + (row * 4 + (ch ^ ((row >> 1) & 3))) * 8];
    }
    #pragma unroll
    for (int i = 0; i < 4; i++)
      #pragma unroll
      for (int j = 0; j < 8; j++)
        acc[i][j] = __builtin_amdgcn_mfma_f32_16x16x32_bf16(
            af[i], bfv[j], acc[i][j], 0, 0, 0);
    __syncthreads();   // drains next A stage + next B loads; guards LDS reuse
    #pragma unroll
    for (int i = 0; i < 4; i++) af[i] = afn[i];
    cur ^= 1;
  }

  // ---- epilogue: 2 row-passes through LDS, coalesced 16B stores ----
  short* CL = &LDS[0];   // [128][256] bf16 = 64KB overlay
  unsigned short* Cu = (unsigned short*)Cout;
  int q = lane >> 4;
  #pragma unroll
  for (int p = 0; p < 2; p++) {
    __syncthreads();
    if (wm == p) {
      #pragma unroll
      for (int j = 0; j < 8; j++) {
        int row = j * 16 + rr;   // local row 0..127
        #pragma unroll
        for (int i = 0; i < 4; i++) {
          int n0 = wn * 64 + i * 16 + q * 4;
          float4 bv = *(const float4*)(bias + col0 + n0);
          ushort4 v = make_ushort4(f2bu(acc[i][j][0] + bv.x),
                                   f2bu(acc[i][j][1] + bv.y),
                                   f2bu(acc[i][j][2] + bv.z),
                                   f2bu(acc[i][j][3] + bv.w));
          int g = n0 >> 2;                       // 8B granule 0..63
          int slot = (g >> 1) ^ (row & 15);      // swizzled 16B slot
          *(ushort4*)(CL + row * 256 + slot * 8 + (g & 1) * 4) = v;
        }
      }
    }
    __syncthreads();
    {
      int row = t >> 2, seg = t & 3;
      int grow = row0 + p * 128 + row;
      if (grow < M) {
        #pragma unroll
        for (int j2 = 0; j2 < 8; j2++) {
          int slot = j2 * 4 + seg;               // logical 16B slot 0..31
          int slot_s = slot ^ (row & 15);
          s8v v = *(const s8v*)(CL + row * 256 + slot_s * 8);
          *(s8v*)&Cu[(size_t)grow * Ncols + col0 + slot * 8] = v;
        }
      }
    }
  }
}

// -------- edge logit helper --------
__device__ __forceinline__ float edge_logit(
    ushort4 u, float d0, float d1, float d2, float d3, float4 at,
    float& f0, float& f1, float& f2, float& f3) {
  f0 = bu2f(u.x); f1 = bu2f(u.y); f2 = bu2f(u.z); f3 = bu2f(u.w);
  float t0 = f0 + d0; t0 = t0 > 0.f ? t0 : 0.2f * t0;
  float t1 = f1 + d1; t1 = t1 > 0.f ? t1 : 0.2f * t1;
  float t2 = f2 + d2; t2 = t2 > 0.f ? t2 : 0.2f * t2;
  float t3 = f3 + d3; t3 = t3 > 0.f ? t3 : 0.2f * t3;
  float lg = t0 * at.x + t1 * at.y + t2 * at.z + t3 * at.w;
  lg += __shfl_xor(lg, 1);
  lg += __shfl_xor(lg, 2);
  lg += __shfl_xor(lg, 4);
  return lg;
}

// -------- branchless online-softmax gather, 4-edge unroll + serial tail -----
__device__ __forceinline__ float4 gat_pass(
    int e0, int e1, const int* __restrict__ csrc,
    const unsigned short* __restrict__ base, size_t stride,
    float d0, float d1, float d2, float d3, float4 at) {
  float m = -1e30f, den = 0.f;
  float a0 = 0.f, a1 = 0.f, a2 = 0.f, a3 = 0.f;
  int e = e0;
  for (; e + 4 <= e1; e += 4) {
    int s0 = csrc[e], s1 = csrc[e + 1], s2 = csrc[e + 2], s3 = csrc[e + 3];
    ushort4 u0 = *(const ushort4*)(base + (size_t)s0 * stride);
    ushort4 u1 = *(const ushort4*)(base + (size_t)s1 * stride);
    ushort4 u2 = *(const ushort4*)(base + (size_t)s2 * stride);
    ushort4 u3 = *(const ushort4*)(base + (size_t)s3 * stride);
    float f0, f1, f2, f3, g0, g1, g2, g3, h0, h1, h2, h3, i0, i1, i2, i3;
    float lg0 = edge_logit(u0, d0, d1, d2, d3, at, f0, f1, f2, f3);
    float lg1 = edge_logit(u1, d0, d1, d2, d3, at, g0, g1, g2, g3);
    float lg2 = edge_logit(u2, d0, d1, d2, d3, at, h0, h1, h2, h3);
    float lg3 = edge_logit(u3, d0, d1, d2, d3, at, i0, i1, i2, i3);
    float mn = fmaxf(fmaxf(fmaxf(lg0, lg1), fmaxf(lg2, lg3)), m);
    float c = __expf(m - mn);
    float x0 = __expf(lg0 - mn);
    float x1 = __expf(lg1 - mn);
    float x2 = __expf(lg2 - mn);
    float x3 = __expf(lg3 - mn);
    den = den * c + x0 + x1 + x2 + x3;
    a0 = a0 * c + x0 * f0 + x1 * g0 + x2 * h0 + x3 * i0;
    a1 = a1 * c + x0 * f1 + x1 * g1 + x2 * h1 + x3 * i1;
    a2 = a2 * c + x0 * f2 + x1 * g2 + x2 * h2 + x3 * i2;
    a3 = a3 * c + x0 * f3 + x1 * g3 + x2 * h3 + x3 * i3;
    m = mn;
  }
  for (; e < e1; ++e) {
    int s0 = csrc[e];
    ushort4 u0 = *(const ushort4*)(base + (size_t)s0 * stride);
    float f0, f1, f2, f3;
    float lg0 = edge_logit(u0, d0, d1, d2, d3, at, f0, f1, f2, f3);
    float mn = fmaxf(m, lg0);
    float c = __expf(m - mn);
    float x0 = __expf(lg0 - mn);
    den = den * c + x0;
    a0 = a0 * c + x0 * f0;
    a1 = a1 * c + x0 * f1;
    a2 = a2 * c + x0 * f2;
    a3 = a3 * c + x0 * f3;
    m = mn;
  }
  float inv = (den > 0.f) ? 1.f / den : 0.f;
  return make_float4(a0 * inv, a1 * inv, a2 * inv, a3 * inv);
}

// -------- node kernel: tile nodes use a WAVE PAIR (road ∥ tb), poi 1 wave ---
__global__ __launch_bounds__(256) void node_gat_all(
    const int* __restrict__ offs, const int* __restrict__ csrc,
    const bf16* __restrict__ F1, const bf16* __restrict__ F2,
    const float* __restrict__ attnL, float scale,
    bf16* __restrict__ ht_n, bf16* __restrict__ hp_n,
    float* __restrict__ outT, float* __restrict__ outP) {
  __shared__ float rbuf[2][64][4];
  int gw = blockIdx.x * 4 + (threadIdx.x >> 6);
  int lane = threadIdx.x & 63;
  int off = (lane >> 3) * DD + (lane & 7) * 4;
  const unsigned short* F1u = (const unsigned short*)F1;
  const unsigned short* F2u = (const unsigned short*)F2;

  if (gw < 2 * NT) {
    int node = gw >> 1;
    int pass = gw & 1;
    int pair = threadIdx.x >> 7;

    const int* po = pass ? (offs + (NT + 1)) : offs;
    const int* pc = pass ? (csrc + NE) : csrc;
    const unsigned short* pb = pass ? (F2u + off) : (F1u + off);
    size_t stride = pass ? 512 : 1024;
    int udofs = pass ? 512 : 256;
    ushort4 ud = *(const ushort4*)(F1u + (size_t)node * 1024 + udofs + off);
    float4 at = *(const float4*)(attnL + (pass ? 256 : 0) + off);

    float4 r = gat_pass(po[node], po[node + 1], pc, pb, stride,
                        bu2f(ud.x), bu2f(ud.y), bu2f(ud.z), bu2f(ud.w), at);

    if (pass) {
      rbuf[pair][lane][0] = r.x; rbuf[pair][lane][1] = r.y;
      rbuf[pair][lane][2] = r.z; rbuf[pair][lane][3] = r.w;
    }
    __syncthreads();
    if (!pass) {
      float v0 = (r.x + rbuf[pair][lane][0]) * scale; v0 = v0 > 0.f ? v0 : 0.f;
      float v1 = (r.y + rbuf[pair][lane][1]) * scale; v1 = v1 > 0.f ? v1 : 0.f;
      float v2 = (r.z + rbuf[pair][lane][2]) * scale; v2 = v2 > 0.f ? v2 : 0.f;
      float v3 = (r.w + rbuf[pair][lane][3]) * scale; v3 = v3 > 0.f ? v3 : 0.f;
      size_t base = (size_t)node * CC + off;
      if (ht_n)
        *(ushort4*)((unsigned short*)ht_n + base) =
            make_ushort4(f2bu(v0), f2bu(v1), f2bu(v2), f2bu(v3));
      if (outT) *(float4*)(outT + base) = make_float4(v0, v1, v2, v3);
    }
  } else {
    int w = gw - 2 * NT;
    const int* offsC = offs + 2 * (NT + 1);
    ushort4 ud = *(const ushort4*)(F2u + (size_t)w * 512 + 256 + off);
    float4 at = *(const float4*)(attnL + 512 + off);
    float4 r = gat_pass(offsC[w], offsC[w + 1], csrc + 2 * (size_t)NE,
                        F1u + 768 + off, 1024,
                        bu2f(ud.x), bu2f(ud.y), bu2f(ud.z), bu2f(ud.w), at);

    float v0 = r.x > 0.f ? r.x : 0.f;
    float v1 = r.y > 0.f ? r.y : 0.f;
    float v2 = r.z > 0.f ? r.z : 0.f;
    float v3 = r.w > 0.f ? r.w : 0.f;

    size_t base = (size_t)w * CC + off;
    if (hp_n)
      *(ushort4*)((unsigned short*)hp_n + base) =
          make_ushort4(f2bu(v0), f2bu(v1), f2bu(v2), f2bu(v3));
    if (outP) *(float4*)(outP + base) = make_float4(v0, v1, v2, v3);
  }
}

extern "C" void kernel_launch(void* const* d_in, const int* in_sizes, int n_in,
                              void* d_out, int out_size, void* d_ws, size_t ws_size,
                              hipStream_t stream) {
  const float* x_tile = (const float*)d_in[0];
  const float* x_poi  = (const float*)d_in[1];
  const int* src_road = (const int*)d_in[2];
  const int* dst_road = (const int*)d_in[3];
  const int* src_tb   = (const int*)d_in[4];
  const int* dst_tb   = (const int*)d_in[5];
  const int* src_ct   = (const int*)d_in[6];
  const int* dst_ct   = (const int*)d_in[7];
  const float* Wsrc[3] = {(const float*)d_in[8],  (const float*)d_in[13], (const float*)d_in[18]};
  const float* bsrc[3] = {(const float*)d_in[9],  (const float*)d_in[14], (const float*)d_in[19]};
  const float* Wdst[3] = {(const float*)d_in[10], (const float*)d_in[15], (const float*)d_in[20]};
  const float* bdst[3] = {(const float*)d_in[11], (const float*)d_in[16], (const float*)d_in[21]};
  const float* attn[3] = {(const float*)d_in[12], (const float*)d_in[17], (const float*)d_in[22]};

  // workspace (~262 MB): ht2/hp2 4x25.6 | F1 102.4 | F2 51.2 | CSR ~3.6 | W ~2
  bf16* hbuf = (bf16*)d_ws;
  bf16* ht2[2] = {hbuf, hbuf + (size_t)NT * CC};
  bf16* hp2[2] = {hbuf + 2 * (size_t)NT * CC, hbuf + 3 * (size_t)NT * CC};
  bf16* F1 = hbuf + 4 * (size_t)NT * CC;
  bf16* F2 = F1 + (size_t)NT * 1024;
  int* offs = (int*)(F2 + (size_t)NT * 512);
  int* deg  = offs + 3 * (NT + 1);
  int* csrc = deg + 3 * NT;
  int* bsum = csrc + (size_t)3 * NE;
  int* boff = bsum + 3 * NBLK;
  uintptr_t wp = ((uintptr_t)(boff + 3 * NBLK) + 63) & ~(uintptr_t)63;
  bf16* W1c[3], *W2c[3];
  {
    bf16* w = (bf16*)wp;
    for (int l = 0; l < 3; l++) {
      int K = (l == 0) ? 128 : 256;
      W1c[l] = w; w += (size_t)1024 * K;
      W2c[l] = w; w += (size_t)512 * K;
    }
    wp = (uintptr_t)w;
  }
  float* b1 = (float*)((wp + 63) & ~(uintptr_t)63);
  float* b2 = b1 + 3 * 1024;

  // input converts (one dispatch for both matrices)
  {
    dim3 gc((NT * 128 + 255) / 256, 2);
    cvt2_f2b<<<gc, 256, 0, stream>>>(x_tile, x_poi, ht2[0], hp2[0], NT * 128);
  }

  // weight + bias prep
  {
    WtArgs wa;
    BiArgs ba;
    for (int l = 0; l < 3; l++) {
      wa.Ws[l] = Wsrc[l]; wa.Wd[l] = Wdst[l];
      wa.W1[l] = W1c[l];  wa.W2[l] = W2c[l];
      ba.bs[l] = bsrc[l]; ba.bd[l] = bdst[l];
    }
    ba.b1 = b1; ba.b2 = b2;
    dim3 gw(256, 6, 3);
    wt_cvt_all<<<gw, 256, 0, stream>>>(wa);
    dim3 gb(6, 3);
    bias_cat<<<gb, 256, 0, stream>>>(ba);
  }

  // CSR build
  zero_i<<<(3 * NT + 255) / 256, 256, 0, stream>>>(deg, 3 * NT);
  {
    dim3 ge((NE + 255) / 256, 3);
    hist3<<<ge, 256, 0, stream>>>(dst_road, dst_tb, dst_ct, deg);
    dim3 gn(NBLK, 3);
    scan_s1<<<gn, 256, 0, stream>>>(deg, bsum);
    scan_s2<<<1, 256, 0, stream>>>(bsum, boff, offs);
    scan_s3<<<gn, 256, 0, stream>>>(deg, boff, offs, deg);
    fill3<<<ge, 256, 0, stream>>>(dst_road, dst_tb, dst_ct,
                                  src_road, src_tb, src_ct, deg, csrc);
  }

  int cb = 0;
  for (int l = 0; l < 3; l++) {
    int K = (l == 0) ? 128 : 256;
    bf16* ht_c = ht2[cb], *hp_c = hp2[cb];
    bf16* ht_n = (l == 2) ? nullptr : ht2[cb ^ 1];
    bf16* hp_n = (l == 2) ? nullptr : hp2[cb ^ 1];
    float st = (l == 1) ? 0.5f : 1.0f;
    float* outT = (l == 2) ? (float*)d_out : nullptr;
    float* outP = (l == 2) ? ((float*)d_out + (size_t)NT * CC) : nullptr;

    int NW = NBLK * 6, q8 = NW / 8, r8 = NW % 8;   // 1176 blocks
    gemm256<<<NW, 512, 0, stream>>>(
        ht_c, W1c[l], b1 + l * 1024, F1,
        hp_c, W2c[l], b2 + l * 512,  F2,
        NT, K, q8, r8);

    // tile waves: 2*NT (pairs), poi waves: NP; boundary block-aligned
    node_gat_all<<<(2 * NT + NP) / 4, 256, 0, stream>>>(
        offs, csrc, F1, F2, attn[l], st, ht_n, hp_n, outT, outP);

    cb ^= 1;
  }
}

// Round 20
// 549.412 us; speedup vs baseline: 1.1059x; 1.1059x over previous
//
#include <hip/hip_runtime.h>
#include <hip/hip_bf16.h>

typedef __hip_bfloat16 bf16;

#define NT 50000
#define NP 50000
#define NE 200000
#define HH 8
#define DD 32
#define CC 256   // H*D
#define NBLK 196 // ceil(NT/256)

typedef short s8v __attribute__((ext_vector_type(8)));   // 8 bf16 (4 VGPRs)
typedef float f4v __attribute__((ext_vector_type(4)));   // 4 f32 acc

__device__ __forceinline__ float bu2f(unsigned short u) {
  return __uint_as_float(((unsigned)u) << 16);
}
__device__ __forceinline__ unsigned short f2bu(float x) {
  bf16 b = __float2bfloat16(x);
  return *(unsigned short*)&b;
}

__device__ __forceinline__ void gload_lds16(const void* g, void* l) {
  __builtin_amdgcn_global_load_lds(
      (const __attribute__((address_space(1))) void*)g,
      (__attribute__((address_space(3))) void*)l, 16, 0, 0);
}

// -------- input convert (both node matrices in one dispatch) --------
__global__ __launch_bounds__(256) void cvt2_f2b(
    const float* __restrict__ a, const float* __restrict__ b,
    bf16* __restrict__ oa, bf16* __restrict__ ob, int n) {
  int i = blockIdx.x * 256 + threadIdx.x;
  if (i >= n) return;
  if (blockIdx.y == 0) oa[i] = __float2bfloat16(a[i]);
  else                 ob[i] = __float2bfloat16(b[i]);
}

// -------- weight prep --------
// W1cat[l] (1024 x K) rows: [Ws rel0 | Wd rel0 | Wd rel1 | Ws rel2]
// W2cat[l] ( 512 x K) rows: [Ws rel1 | Wd rel2]
struct WtArgs {
  const float* Ws[3]; const float* Wd[3];
  bf16* W1[3]; bf16* W2[3];
};
__global__ __launch_bounds__(256) void wt_cvt_all(WtArgs a) {
  int l = blockIdx.z, y = blockIdx.y;
  int K = (l == 0) ? 128 : 256;
  int idx = blockIdx.x * 256 + threadIdx.x;
  if (idx >= 256 * K) return;
  int n = idx / K, k = idx - n * K;
  const float* W; bf16* D; int dn;
  if (y == 0)      { W = a.Ws[l];                       D = a.W1[l]; dn = n; }
  else if (y == 1) { W = a.Wd[l];                       D = a.W1[l]; dn = n + 256; }
  else if (y == 2) { W = a.Wd[l] + (size_t)1 * K * 256; D = a.W1[l]; dn = n + 512; }
  else if (y == 3) { W = a.Ws[l] + (size_t)2 * K * 256; D = a.W1[l]; dn = n + 768; }
  else if (y == 4) { W = a.Ws[l] + (size_t)1 * K * 256; D = a.W2[l]; dn = n; }
  else             { W = a.Wd[l] + (size_t)2 * K * 256; D = a.W2[l]; dn = n + 256; }
  D[(size_t)dn * K + k] = __float2bfloat16(W[(size_t)k * 256 + n]);
}

struct BiArgs {
  const float* bs[3]; const float* bd[3];
  float* b1; float* b2;  // b1: 3*1024, b2: 3*512
};
__global__ __launch_bounds__(256) void bias_cat(BiArgs a) {
  int l = blockIdx.y, y = blockIdx.x;
  int n = threadIdx.x;
  float v;
  if (y == 0)      v = a.bs[l][n];
  else if (y == 1) v = a.bd[l][n];
  else if (y == 2) v = a.bd[l][256 + n];
  else if (y == 3) v = a.bs[l][512 + n];
  else if (y == 4) v = a.bs[l][256 + n];
  else             v = a.bd[l][512 + n];
  if (y < 4) a.b1[l * 1024 + y * 256 + n] = v;
  else       a.b2[l * 512 + (y - 4) * 256 + n] = v;
}

__global__ __launch_bounds__(256) void zero_i(int* __restrict__ p, int n) {
  int i = blockIdx.x * 256 + threadIdx.x;
  if (i < n) p[i] = 0;
}

// -------- CSR build (batched over 3 relations via blockIdx.y) --------
__global__ __launch_bounds__(256) void hist3(
    const int* __restrict__ d0, const int* __restrict__ d1,
    const int* __restrict__ d2, int* __restrict__ deg) {
  int r = blockIdx.y;
  int e = blockIdx.x * 256 + threadIdx.x;
  if (e >= NE) return;
  const int* d = (r == 0) ? d0 : (r == 1) ? d1 : d2;
  atomicAdd(&deg[r * NT + d[e]], 1);
}

__global__ __launch_bounds__(256) void scan_s1(const int* __restrict__ deg,
                                               int* __restrict__ bsum) {
  __shared__ int buf[256];
  int r = blockIdx.y, b = blockIdx.x, t = threadIdx.x;
  int idx = b * 256 + t;
  buf[t] = (idx < NT) ? deg[r * NT + idx] : 0;
  __syncthreads();
  for (int s = 128; s > 0; s >>= 1) {
    if (t < s) buf[t] += buf[t + s];
    __syncthreads();
  }
  if (t == 0) bsum[r * NBLK + b] = buf[0];
}

__global__ __launch_bounds__(256) void scan_s2(
    const int* __restrict__ bsum, int* __restrict__ boff,
    int* __restrict__ offs) {
  __shared__ int buf[256];
  int t = threadIdx.x;
  for (int r = 0; r < 3; r++) {
    int v = (t < NBLK) ? bsum[r * NBLK + t] : 0;
    buf[t] = v;
    __syncthreads();
    for (int s = 1; s < 256; s <<= 1) {
      int u = (t >= s) ? buf[t - s] : 0;
      __syncthreads();
      buf[t] += u;
      __syncthreads();
    }
    if (t < NBLK) boff[r * NBLK + t] = buf[t] - v;
    if (t == 255) offs[(size_t)r * (NT + 1) + NT] = buf[255];
    __syncthreads();
  }
}

__global__ __launch_bounds__(256) void scan_s3(
    const int* __restrict__ deg, const int* __restrict__ boff,
    int* __restrict__ offs, int* __restrict__ cursor) {
  __shared__ int buf[256];
  int r = blockIdx.y, b = blockIdx.x, t = threadIdx.x;
  int idx = b * 256 + t;
  int v = (idx < NT) ? deg[r * NT + idx] : 0;
  buf[t] = v;
  __syncthreads();
  for (int s = 1; s < 256; s <<= 1) {
    int u = (t >= s) ? buf[t - s] : 0;
    __syncthreads();
    buf[t] += u;
    __syncthreads();
  }
  int o = boff[r * NBLK + b] + buf[t] - v;
  if (idx < NT) {
    offs[(size_t)r * (NT + 1) + idx] = o;
    cursor[r * NT + idx] = o;
  }
}

__global__ __launch_bounds__(256) void fill3(
    const int* __restrict__ d0, const int* __restrict__ d1,
    const int* __restrict__ d2, const int* __restrict__ s0,
    const int* __restrict__ s1, const int* __restrict__ s2,
    int* __restrict__ cursor, int* __restrict__ csrc) {
  int r = blockIdx.y;
  int e = blockIdx.x * 256 + threadIdx.x;
  if (e >= NE) return;
  const int* d = (r == 0) ? d0 : (r == 1) ? d1 : d2;
  const int* s = (r == 0) ? s0 : (r == 1) ? s1 : s2;
  int p = atomicAdd(&cursor[r * NT + d[e]], 1);
  csrc[(size_t)r * NE + p] = s[e];
}

// -------- 256x256 MFMA GEMM, counted-vmcnt pipeline (T4) ---------------
__global__ __launch_bounds__(512, 2) void gemm256(
    const bf16* __restrict__ A1, const bf16* __restrict__ B1t,
    const float* __restrict__ bias1, bf16* __restrict__ C1,
    const bf16* __restrict__ A2, const bf16* __restrict__ B2t,
    const float* __restrict__ bias2, bf16* __restrict__ C2,
    int M, int K, int q8, int r8) {
  __shared__ short LDS[2][2][8192];   // 64KB staging; reused as [128][256] C tile
  int bid = blockIdx.x;
  int xcd = bid & 7, pos = bid >> 3;
  int wg = (xcd < r8 ? xcd * (q8 + 1) : r8 * (q8 + 1) + (xcd - r8) * q8) + pos;
  int bm = wg / 6, bn = wg - bm * 6;

  const bf16* A; const bf16* Bt; const float* bias; bf16* Cout; int Ncols, col0;
  if (bn < 4) { A = A1; Bt = B1t + (size_t)bn * 256 * K; bias = bias1; Cout = C1; Ncols = 1024; col0 = bn * 256; }
  else { A = A2; Bt = B2t + (size_t)(bn - 4) * 256 * K; bias = bias2; Cout = C2; Ncols = 512; col0 = (bn - 4) * 256; }

  int t = threadIdx.x;
  int lane = t & 63;
  int wid = t >> 6;
  int wm = wid >> 2, wn = wid & 3;   // 2 x 4 wave grid
  int row0 = bm * 256;
  int wbase = t & ~63;

  f4v acc[4][8] = {};   // [i: N-frag][j: M-frag]

  const bf16* Abase = A + (size_t)row0 * K;

  auto stage = [&](int buf, int kt) {
    int kofs = kt * 32;
    #pragma unroll
    for (int j = 0; j < 2; j++) {
      int s = j * 512 + t;
      int row = s >> 2, ch = s & 3;
      int sch = ch ^ ((row >> 1) & 3);
      gload_lds16(Abase + (size_t)row * K + kofs + sch * 8,
                  &LDS[buf][0][(j * 512 + wbase) * 8]);
    }
    #pragma unroll
    for (int j = 0; j < 2; j++) {
      int s = j * 512 + t;
      int row = s >> 2, ch = s & 3;
      int sch = ch ^ ((row >> 1) & 3);
      gload_lds16(Bt + (size_t)row * K + kofs + sch * 8,
                  &LDS[buf][1][(j * 512 + wbase) * 8]);
    }
  };

  int nk = K / 32;   // 4 or 8
  stage(0, 0);
  stage(1, 1);
  asm volatile("s_waitcnt vmcnt(4)" ::: "memory");
  __builtin_amdgcn_s_barrier();
  __builtin_amdgcn_sched_barrier(0);

  int cur = 0;
  for (int kt = 0; kt < nk; kt++) {
    int ch = lane >> 4;
    int rr = lane & 15;
    s8v af[4], bfv[8];
    #pragma unroll
    for (int i = 0; i < 4; i++) {
      int row = wn * 64 + i * 16 + rr;
      af[i] = *(const s8v*)&LDS[cur][1][(row * 4 + (ch ^ ((row >> 1) & 3))) * 8];
    }
    #pragma unroll
    for (int j = 0; j < 8; j++) {
      int row = wm * 128 + j * 16 + rr;
      bfv[j] = *(const s8v*)&LDS[cur][0][(row * 4 + (ch ^ ((row >> 1) & 3))) * 8];
    }
    asm volatile("s_waitcnt lgkmcnt(0)" ::: "memory");
    __builtin_amdgcn_s_barrier();          // all waves done reading buf[cur]
    __builtin_amdgcn_sched_barrier(0);
    bool staged = (kt + 2 < nk);
    if (staged) stage(cur, kt + 2);
    #pragma unroll
    for (int i = 0; i < 4; i++)
      #pragma unroll
      for (int j = 0; j < 8; j++)
        acc[i][j] = __builtin_amdgcn_mfma_f32_16x16x32_bf16(
            af[i], bfv[j], acc[i][j], 0, 0, 0);
    if (kt + 1 < nk) {
      if (staged) {
        asm volatile("s_waitcnt vmcnt(4)" ::: "memory");
      } else {
        asm volatile("s_waitcnt vmcnt(0)" ::: "memory");
      }
      __builtin_amdgcn_s_barrier();
      __builtin_amdgcn_sched_barrier(0);
    }
    cur ^= 1;
  }

  // ---- epilogue: 2 row-passes through LDS, coalesced 16B stores ----
  short* CL = &LDS[0][0][0];   // [128][256] bf16 = 64KB
  unsigned short* Cu = (unsigned short*)Cout;
  int q = lane >> 4, rr = lane & 15;
  #pragma unroll
  for (int p = 0; p < 2; p++) {
    __syncthreads();
    if (wm == p) {
      #pragma unroll
      for (int j = 0; j < 8; j++) {
        int row = j * 16 + rr;   // local row 0..127
        #pragma unroll
        for (int i = 0; i < 4; i++) {
          int n0 = wn * 64 + i * 16 + q * 4;
          float4 bv = *(const float4*)(bias + col0 + n0);
          ushort4 v = make_ushort4(f2bu(acc[i][j][0] + bv.x),
                                   f2bu(acc[i][j][1] + bv.y),
                                   f2bu(acc[i][j][2] + bv.z),
                                   f2bu(acc[i][j][3] + bv.w));
          int g = n0 >> 2;                       // 8B granule 0..63
          int slot = (g >> 1) ^ (row & 15);      // swizzled 16B slot
          *(ushort4*)(CL + row * 256 + slot * 8 + (g & 1) * 4) = v;
        }
      }
    }
    __syncthreads();
    {
      int row = t >> 2, seg = t & 3;
      int grow = row0 + p * 128 + row;
      if (grow < M) {
        #pragma unroll
        for (int j2 = 0; j2 < 8; j2++) {
          int slot = j2 * 4 + seg;               // logical 16B slot 0..31
          int slot_s = slot ^ (row & 15);
          s8v v = *(const s8v*)(CL + row * 256 + slot_s * 8);
          *(s8v*)&Cu[(size_t)grow * Ncols + col0 + slot * 8] = v;
        }
      }
    }
  }
}

// -------- edge logit helper --------
__device__ __forceinline__ float edge_logit(
    ushort4 u, float d0, float d1, float d2, float d3, float4 at,
    float& f0, float& f1, float& f2, float& f3) {
  f0 = bu2f(u.x); f1 = bu2f(u.y); f2 = bu2f(u.z); f3 = bu2f(u.w);
  float t0 = f0 + d0; t0 = t0 > 0.f ? t0 : 0.2f * t0;
  float t1 = f1 + d1; t1 = t1 > 0.f ? t1 : 0.2f * t1;
  float t2 = f2 + d2; t2 = t2 > 0.f ? t2 : 0.2f * t2;
  float t3 = f3 + d3; t3 = t3 > 0.f ? t3 : 0.2f * t3;
  float lg = t0 * at.x + t1 * at.y + t2 * at.z + t3 * at.w;
  lg += __shfl_xor(lg, 1);
  lg += __shfl_xor(lg, 2);
  lg += __shfl_xor(lg, 4);
  return lg;
}

// -------- branchless online-softmax gather, 4-edge unroll + serial tail -----
__device__ __forceinline__ float4 gat_pass(
    int e0, int e1, const int* __restrict__ csrc,
    const unsigned short* __restrict__ base, size_t stride,
    float d0, float d1, float d2, float d3, float4 at) {
  float m = -1e30f, den = 0.f;
  float a0 = 0.f, a1 = 0.f, a2 = 0.f, a3 = 0.f;
  int e = e0;
  for (; e + 4 <= e1; e += 4) {
    int s0 = csrc[e], s1 = csrc[e + 1], s2 = csrc[e + 2], s3 = csrc[e + 3];
    ushort4 u0 = *(const ushort4*)(base + (size_t)s0 * stride);
    ushort4 u1 = *(const ushort4*)(base + (size_t)s1 * stride);
    ushort4 u2 = *(const ushort4*)(base + (size_t)s2 * stride);
    ushort4 u3 = *(const ushort4*)(base + (size_t)s3 * stride);
    float f0, f1, f2, f3, g0, g1, g2, g3, h0, h1, h2, h3, i0, i1, i2, i3;
    float lg0 = edge_logit(u0, d0, d1, d2, d3, at, f0, f1, f2, f3);
    float lg1 = edge_logit(u1, d0, d1, d2, d3, at, g0, g1, g2, g3);
    float lg2 = edge_logit(u2, d0, d1, d2, d3, at, h0, h1, h2, h3);
    float lg3 = edge_logit(u3, d0, d1, d2, d3, at, i0, i1, i2, i3);
    float mn = fmaxf(fmaxf(fmaxf(lg0, lg1), fmaxf(lg2, lg3)), m);
    float c = __expf(m - mn);
    float x0 = __expf(lg0 - mn);
    float x1 = __expf(lg1 - mn);
    float x2 = __expf(lg2 - mn);
    float x3 = __expf(lg3 - mn);
    den = den * c + x0 + x1 + x2 + x3;
    a0 = a0 * c + x0 * f0 + x1 * g0 + x2 * h0 + x3 * i0;
    a1 = a1 * c + x0 * f1 + x1 * g1 + x2 * h1 + x3 * i1;
    a2 = a2 * c + x0 * f2 + x1 * g2 + x2 * h2 + x3 * i2;
    a3 = a3 * c + x0 * f3 + x1 * g3 + x2 * h3 + x3 * i3;
    m = mn;
  }
  for (; e < e1; ++e) {
    int s0 = csrc[e];
    ushort4 u0 = *(const ushort4*)(base + (size_t)s0 * stride);
    float f0, f1, f2, f3;
    float lg0 = edge_logit(u0, d0, d1, d2, d3, at, f0, f1, f2, f3);
    float mn = fmaxf(m, lg0);
    float c = __expf(m - mn);
    float x0 = __expf(lg0 - mn);
    den = den * c + x0;
    a0 = a0 * c + x0 * f0;
    a1 = a1 * c + x0 * f1;
    a2 = a2 * c + x0 * f2;
    a3 = a3 * c + x0 * f3;
    m = mn;
  }
  float inv = (den > 0.f) ? 1.f / den : 0.f;
  return make_float4(a0 * inv, a1 * inv, a2 * inv, a3 * inv);
}

// -------- node kernel: tile nodes use a WAVE PAIR (road ∥ tb), poi 1 wave ---
__global__ __launch_bounds__(256) void node_gat_all(
    const int* __restrict__ offs, const int* __restrict__ csrc,
    const bf16* __restrict__ F1, const bf16* __restrict__ F2,
    const float* __restrict__ attnL, float scale,
    bf16* __restrict__ ht_n, bf16* __restrict__ hp_n,
    float* __restrict__ outT, float* __restrict__ outP) {
  __shared__ float rbuf[2][64][4];
  int gw = blockIdx.x * 4 + (threadIdx.x >> 6);
  int lane = threadIdx.x & 63;
  int off = (lane >> 3) * DD + (lane & 7) * 4;
  const unsigned short* F1u = (const unsigned short*)F1;
  const unsigned short* F2u = (const unsigned short*)F2;

  if (gw < 2 * NT) {
    int node = gw >> 1;
    int pass = gw & 1;
    int pair = threadIdx.x >> 7;

    const int* po = pass ? (offs + (NT + 1)) : offs;
    const int* pc = pass ? (csrc + NE) : csrc;
    const unsigned short* pb = pass ? (F2u + off) : (F1u + off);
    size_t stride = pass ? 512 : 1024;
    int udofs = pass ? 512 : 256;
    ushort4 ud = *(const ushort4*)(F1u + (size_t)node * 1024 + udofs + off);
    float4 at = *(const float4*)(attnL + (pass ? 256 : 0) + off);

    float4 r = gat_pass(po[node], po[node + 1], pc, pb, stride,
                        bu2f(ud.x), bu2f(ud.y), bu2f(ud.z), bu2f(ud.w), at);

    if (pass) {
      rbuf[pair][lane][0] = r.x; rbuf[pair][lane][1] = r.y;
      rbuf[pair][lane][2] = r.z; rbuf[pair][lane][3] = r.w;
    }
    __syncthreads();
    if (!pass) {
      float v0 = (r.x + rbuf[pair][lane][0]) * scale; v0 = v0 > 0.f ? v0 : 0.f;
      float v1 = (r.y + rbuf[pair][lane][1]) * scale; v1 = v1 > 0.f ? v1 : 0.f;
      float v2 = (r.z + rbuf[pair][lane][2]) * scale; v2 = v2 > 0.f ? v2 : 0.f;
      float v3 = (r.w + rbuf[pair][lane][3]) * scale; v3 = v3 > 0.f ? v3 : 0.f;
      size_t base = (size_t)node * CC + off;
      if (ht_n)
        *(ushort4*)((unsigned short*)ht_n + base) =
            make_ushort4(f2bu(v0), f2bu(v1), f2bu(v2), f2bu(v3));
      if (outT) *(float4*)(outT + base) = make_float4(v0, v1, v2, v3);
    }
  } else {
    int w = gw - 2 * NT;
    const int* offsC = offs + 2 * (NT + 1);
    ushort4 ud = *(const ushort4*)(F2u + (size_t)w * 512 + 256 + off);
    float4 at = *(const float4*)(attnL + 512 + off);
    float4 r = gat_pass(offsC[w], offsC[w + 1], csrc + 2 * (size_t)NE,
                        F1u + 768 + off, 1024,
                        bu2f(ud.x), bu2f(ud.y), bu2f(ud.z), bu2f(ud.w), at);

    float v0 = r.x > 0.f ? r.x : 0.f;
    float v1 = r.y > 0.f ? r.y : 0.f;
    float v2 = r.z > 0.f ? r.z : 0.f;
    float v3 = r.w > 0.f ? r.w : 0.f;

    size_t base = (size_t)w * CC + off;
    if (hp_n)
      *(ushort4*)((unsigned short*)hp_n + base) =
          make_ushort4(f2bu(v0), f2bu(v1), f2bu(v2), f2bu(v3));
    if (outP) *(float4*)(outP + base) = make_float4(v0, v1, v2, v3);
  }
}

extern "C" void kernel_launch(void* const* d_in, const int* in_sizes, int n_in,
                              void* d_out, int out_size, void* d_ws, size_t ws_size,
                              hipStream_t stream) {
  const float* x_tile = (const float*)d_in[0];
  const float* x_poi  = (const float*)d_in[1];
  const int* src_road = (const int*)d_in[2];
  const int* dst_road = (const int*)d_in[3];
  const int* src_tb   = (const int*)d_in[4];
  const int* dst_tb   = (const int*)d_in[5];
  const int* src_ct   = (const int*)d_in[6];
  const int* dst_ct   = (const int*)d_in[7];
  const float* Wsrc[3] = {(const float*)d_in[8],  (const float*)d_in[13], (const float*)d_in[18]};
  const float* bsrc[3] = {(const float*)d_in[9],  (const float*)d_in[14], (const float*)d_in[19]};
  const float* Wdst[3] = {(const float*)d_in[10], (const float*)d_in[15], (const float*)d_in[20]};
  const float* bdst[3] = {(const float*)d_in[11], (const float*)d_in[16], (const float*)d_in[21]};
  const float* attn[3] = {(const float*)d_in[12], (const float*)d_in[17], (const float*)d_in[22]};

  // workspace (~262 MB): ht2/hp2 4x25.6 | F1 102.4 | F2 51.2 | CSR ~3.6 | W ~2
  bf16* hbuf = (bf16*)d_ws;
  bf16* ht2[2] = {hbuf, hbuf + (size_t)NT * CC};
  bf16* hp2[2] = {hbuf + 2 * (size_t)NT * CC, hbuf + 3 * (size_t)NT * CC};
  bf16* F1 = hbuf + 4 * (size_t)NT * CC;
  bf16* F2 = F1 + (size_t)NT * 1024;
  int* offs = (int*)(F2 + (size_t)NT * 512);
  int* deg  = offs + 3 * (NT + 1);
  int* csrc = deg + 3 * NT;
  int* bsum = csrc + (size_t)3 * NE;
  int* boff = bsum + 3 * NBLK;
  uintptr_t wp = ((uintptr_t)(boff + 3 * NBLK) + 63) & ~(uintptr_t)63;
  bf16* W1c[3], *W2c[3];
  {
    bf16* w = (bf16*)wp;
    for (int l = 0; l < 3; l++) {
      int K = (l == 0) ? 128 : 256;
      W1c[l] = w; w += (size_t)1024 * K;
      W2c[l] = w; w += (size_t)512 * K;
    }
    wp = (uintptr_t)w;
  }
  float* b1 = (float*)((wp + 63) & ~(uintptr_t)63);
  float* b2 = b1 + 3 * 1024;

  // input converts (one dispatch for both matrices)
  {
    dim3 gc((NT * 128 + 255) / 256, 2);
    cvt2_f2b<<<gc, 256, 0, stream>>>(x_tile, x_poi, ht2[0], hp2[0], NT * 128);
  }

  // weight + bias prep
  {
    WtArgs wa;
    BiArgs ba;
    for (int l = 0; l < 3; l++) {
      wa.Ws[l] = Wsrc[l]; wa.Wd[l] = Wdst[l];
      wa.W1[l] = W1c[l];  wa.W2[l] = W2c[l];
      ba.bs[l] = bsrc[l]; ba.bd[l] = bdst[l];
    }
    ba.b1 = b1; ba.b2 = b2;
    dim3 gw(256, 6, 3);
    wt_cvt_all<<<gw, 256, 0, stream>>>(wa);
    dim3 gb(6, 3);
    bias_cat<<<gb, 256, 0, stream>>>(ba);
  }

  // CSR build
  zero_i<<<(3 * NT + 255) / 256, 256, 0, stream>>>(deg, 3 * NT);
  {
    dim3 ge((NE + 255) / 256, 3);
    hist3<<<ge, 256, 0, stream>>>(dst_road, dst_tb, dst_ct, deg);
    dim3 gn(NBLK, 3);
    scan_s1<<<gn, 256, 0, stream>>>(deg, bsum);
    scan_s2<<<1, 256, 0, stream>>>(bsum, boff, offs);
    scan_s3<<<gn, 256, 0, stream>>>(deg, boff, offs, deg);
    fill3<<<ge, 256, 0, stream>>>(dst_road, dst_tb, dst_ct,
                                  src_road, src_tb, src_ct, deg, csrc);
  }

  int cb = 0;
  for (int l = 0; l < 3; l++) {
    int K = (l == 0) ? 128 : 256;
    bf16* ht_c = ht2[cb], *hp_c = hp2[cb];
    bf16* ht_n = (l == 2) ? nullptr : ht2[cb ^ 1];
    bf16* hp_n = (l == 2) ? nullptr : hp2[cb ^ 1];
    float st = (l == 1) ? 0.5f : 1.0f;
    float* outT = (l == 2) ? (float*)d_out : nullptr;
    float* outP = (l == 2) ? ((float*)d_out + (size_t)NT * CC) : nullptr;

    int NW = NBLK * 6, q8 = NW / 8, r8 = NW % 8;   // 1176 blocks
    gemm256<<<NW, 512, 0, stream>>>(
        ht_c, W1c[l], b1 + l * 1024, F1,
        hp_c, W2c[l], b2 + l * 512,  F2,
        NT, K, q8, r8);

    // tile waves: 2*NT (pairs), poi waves: NP; boundary block-aligned
    node_gat_all<<<(2 * NT + NP) / 4, 256, 0, stream>>>(
        offs, csrc, F1, F2, attn[l], st, ht_n, hp_n, outT, outP);

    cb ^= 1;
  }
}